// Round 10
// baseline (213.810 us; speedup 1.0000x reference)
//
#include <hip/hip_runtime.h>
#include <cmath>

typedef __attribute__((ext_vector_type(8))) short short8;
typedef __attribute__((ext_vector_type(4))) short short4v;
typedef __attribute__((ext_vector_type(4))) float float4v;
typedef __attribute__((ext_vector_type(4))) int int4v;
typedef unsigned short ushort_t;

#define LSEQ   2048
#define DMODEL 1024
#define BM 128
#define BN 128
#define BK 64
#define TPAD 136

// log2(0.96875)
#define L2GAMMA (-0.045803595f)
// log2(10000)/512
#define L2E4_512 (0.0259525632f)

__device__ __forceinline__ ushort_t f2b(float x) {
    union { float f; unsigned u; } v; v.f = x;
    unsigned r = v.u + 0x7fffu + ((v.u >> 16) & 1u);
    return (ushort_t)(r >> 16);
}

#define GLOAD_LDS16(gptr, lptr)                                                     \
    __builtin_amdgcn_global_load_lds(                                               \
        (const __attribute__((address_space(1))) unsigned int*)(gptr),              \
        (__attribute__((address_space(3))) unsigned int*)(lptr), 16, 0, 0)

#define MFMA16 __builtin_amdgcn_mfma_f32_16x16x32_bf16

__device__ __forceinline__ short8 as8(int4v v) {
    return __builtin_bit_cast(short8, v);
}

// ds_read_b128 with compile-time immediate offset
#define DSRN(dst, areg, imm) \
    asm volatile("ds_read_b128 %0, %1 offset:%c2" : "=v"(dst) : "v"(areg), "n"(imm))

// ---------------------------------------------------------------------------
// Shared GEMM core (R7/R8-verified): 16x16x32, 128x128 tile, 4 waves,
// dbuf + counted vmcnt(8) + raw barriers. Used by score/av.
// ---------------------------------------------------------------------------
__device__ __forceinline__ void gemm16_core(
    const ushort_t* __restrict__ Ag, int lda, int aRow0,
    const ushort_t* __restrict__ Bg, int ldb, int bRow0,
    int kDepth, ushort_t* As, ushort_t* Bs, float4v acc[4][4])
{
    const int tid  = threadIdx.x;
    const int wave = tid >> 6, lane = tid & 63;
    const int wm = wave >> 1, wn = wave & 1;
    const int l15 = lane & 15, l4g = lane >> 4, l7 = lane & 7;
    const int srow = lane >> 3;
    const int scol = ((lane & 7) ^ srow) * 8;

    const ushort_t* ap[4];
    const ushort_t* bp[4];
    #pragma unroll
    for (int L = 0; L < 4; ++L) {
        int r = (wave * 4 + L) * 8 + srow;
        ap[L] = Ag + (size_t)(aRow0 + r) * lda + scol;
        bp[L] = Bg + (size_t)(bRow0 + r) * ldb + scol;
    }
    const int ldst = srow * BK + (lane & 7) * 8;

    int aBase[2], bBase[2];
    #pragma unroll
    for (int h = 0; h < 2; ++h) {
        const int ch = ((h * 4 + l4g) ^ l7) * 8;
        aBase[h] = (wm * 64 + l15) * BK + ch;
        bBase[h] = (wn * 64 + l15) * BK + ch;
    }

    const int nt = kDepth / BK;
    #pragma unroll
    for (int L = 0; L < 4; ++L) {
        GLOAD_LDS16(ap[L], As + (wave * 4 + L) * (8 * BK) + ldst);
        GLOAD_LDS16(bp[L], Bs + (wave * 4 + L) * (8 * BK) + ldst);
        ap[L] += BK; bp[L] += BK;
    }

    for (int j = 0; j < nt; ++j) {
        const int cur = (j & 1) * (BM * BK);
        const int nxt = ((j + 1) & 1) * (BM * BK);
        if (j + 1 < nt) {
            #pragma unroll
            for (int L = 0; L < 4; ++L) {
                GLOAD_LDS16(ap[L], As + nxt + (wave * 4 + L) * (8 * BK) + ldst);
                GLOAD_LDS16(bp[L], Bs + nxt + (wave * 4 + L) * (8 * BK) + ldst);
                ap[L] += BK; bp[L] += BK;
            }
            asm volatile("s_waitcnt vmcnt(8)" ::: "memory");
        } else {
            asm volatile("s_waitcnt vmcnt(0)" ::: "memory");
        }
        __builtin_amdgcn_s_barrier();
        asm volatile("" ::: "memory");

        #pragma unroll
        for (int h = 0; h < 2; ++h) {
            short8 a[4], b[4];
            #pragma unroll
            for (int f = 0; f < 4; ++f) {
                a[f] = *(const short8*)(As + cur + aBase[h] + f * (16 * BK));
                b[f] = *(const short8*)(Bs + cur + bBase[h] + f * (16 * BK));
            }
            #pragma unroll
            for (int fr = 0; fr < 4; ++fr)
                #pragma unroll
                for (int fc = 0; fc < 4; ++fc)
                    acc[fr][fc] = MFMA16(a[fr], b[fc], acc[fr][fc], 0, 0, 0);
        }
        asm volatile("" ::: "memory");
        __builtin_amdgcn_s_barrier();
    }
}

// ---------------------------------------------------------------------------
// Merged prep (single dispatch)
// ---------------------------------------------------------------------------
__global__ __launch_bounds__(256) void prep_kernel(
    float2* __restrict__ T,
    const float* __restrict__ Wq, const float* __restrict__ Wk,
    const float* __restrict__ Wv, ushort_t* __restrict__ Wt,
    const float4* __restrict__ X, short4v* __restrict__ Xb, int n4)
{
    __shared__ float t[32][33];
    const int bid = blockIdx.x;
    if (bid < 8192) {
        int idx = bid * 256 + threadIdx.x;
        int l = idx & 2047;
        int p = (idx >> 11) & 511;
        int mode = idx >> 20;
        float sv = (2.0f * (float)p + 409.6f) * (1.0f / 1433.6f);
        float coeff = log2f(sv) * (1.0f / 512.0f) + L2GAMMA;
        float invf = exp2f(-(float)p * L2E4_512);
        float lf = (float)l;
        float s, c;
        sincosf(lf * invf, &s, &c);
        float g = exp2f((mode == 0 ? lf : -lf) * coeff);
        T[idx] = make_float2(c * g, s * g);
    } else if (bid < 11264) {
        const int wb = bid - 8192;
        const int bz = wb >> 10;
        const int rem = wb & 1023;
        const int by = rem >> 5, bx = rem & 31;
        const float* W = bz == 0 ? Wq : bz == 1 ? Wk : Wv;
        ushort_t* O = Wt + (size_t)bz * (DMODEL * DMODEL);
        const int x = threadIdx.x & 31, y = (threadIdx.x >> 5) * 4;
        const int k0 = by * 32, n0 = bx * 32;
        #pragma unroll
        for (int j = 0; j < 4; ++j)
            t[y + j][x] = W[(size_t)(k0 + y + j) * DMODEL + n0 + x];
        __syncthreads();
        #pragma unroll
        for (int j = 0; j < 4; ++j)
            O[(size_t)(n0 + y + j) * DMODEL + k0 + x] = f2b(t[x][y + j]);
    } else {
        int i = (bid - 11264) * 256 + threadIdx.x;
        if (i < n4) {
            float4 v = X[i];
            short4v o;
            o.x = (short)f2b(v.x); o.y = (short)f2b(v.y);
            o.z = (short)f2b(v.z); o.w = (short)f2b(v.w);
            Xb[i] = o;
        }
    }
}

// ---------------------------------------------------------------------------
// Fallback Stage 1 (R7-verified 128x128 qkv).
// ---------------------------------------------------------------------------
__global__ __launch_bounds__(256) void qkv16_kernel(
    const ushort_t* __restrict__ Xb, const ushort_t* __restrict__ Wt,
    const float2* __restrict__ Tab,
    ushort_t* __restrict__ Q, ushort_t* __restrict__ Ko, ushort_t* __restrict__ Vt)
{
    __shared__ ushort_t smem[32768];
    ushort_t* As = smem;
    ushort_t* Bs = smem + 16384;

    const int nwg = gridDim.x;
    const int orig = blockIdx.x;
    const int lin = (orig & 7) * (nwg >> 3) + (orig >> 3);
    const int inner = lin & 63;
    const int sup = lin >> 6;
    const int c = (sup % 3) * 8 + (inner & 7);
    const int r = (sup / 3) * 8 + (inner >> 3);
    const int mode = c >> 3;
    const int c0 = (c & 7) * BN;
    const int row0 = r * BM;

    const int tid = threadIdx.x;
    const int wave = tid >> 6, lane = tid & 63;
    const int wm = wave >> 1, wn = wave & 1;
    const int l15 = lane & 15, l4g = lane >> 4, l7 = lane & 7;

    const int srow = lane >> 3;
    const int scol = ((lane & 7) ^ srow) * 8;
    const char* gA = (const char*)Xb;
    const char* gB = (const char*)(Wt + (size_t)mode * (DMODEL * DMODEL));
    unsigned aoff[4], boff[4];
    #pragma unroll
    for (int L = 0; L < 4; ++L) {
        const int rr = (wave * 4 + L) * 8 + srow;
        aoff[L] = (unsigned)(((row0 + rr) * DMODEL + scol) * 2);
        boff[L] = (unsigned)(((c0 + rr) * DMODEL + scol) * 2);
    }
    const int ldst = srow * BK + (lane & 7) * 8;

    int aBase[2], bBase[2];
    #pragma unroll
    for (int h = 0; h < 2; ++h) {
        const int ch = ((h * 4 + l4g) ^ l7) * 8;
        aBase[h] = (wm * 64 + l15) * BK + ch;
        bBase[h] = (wn * 64 + l15) * BK + ch;
    }

    float4v acc[4][4] = {};

    #pragma unroll
    for (int L = 0; L < 4; ++L) {
        GLOAD_LDS16(gA + aoff[L], As + (wave * 4 + L) * (8 * BK) + ldst);
        GLOAD_LDS16(gB + boff[L], Bs + (wave * 4 + L) * (8 * BK) + ldst);
        aoff[L] += 2 * BK; boff[L] += 2 * BK;
    }

    #pragma unroll 2
    for (int k = 0; k < 16; ++k) {
        const int cur = (k & 1) * (BM * BK);
        const int nxt = ((k + 1) & 1) * (BM * BK);
        if (k < 15) {
            #pragma unroll
            for (int L = 0; L < 4; ++L) {
                GLOAD_LDS16(gA + aoff[L], As + nxt + (wave * 4 + L) * (8 * BK) + ldst);
                GLOAD_LDS16(gB + boff[L], Bs + nxt + (wave * 4 + L) * (8 * BK) + ldst);
                aoff[L] += 2 * BK; boff[L] += 2 * BK;
            }
            asm volatile("s_waitcnt vmcnt(8)" ::: "memory");
        } else {
            asm volatile("s_waitcnt vmcnt(0)" ::: "memory");
        }
        __builtin_amdgcn_s_barrier();
        asm volatile("" ::: "memory");

        #pragma unroll
        for (int h = 0; h < 2; ++h) {
            short8 a[4], b[4];
            #pragma unroll
            for (int f = 0; f < 4; ++f) {
                a[f] = *(const short8*)(As + cur + aBase[h] + f * (16 * BK));
                b[f] = *(const short8*)(Bs + cur + bBase[h] + f * (16 * BK));
            }
            #pragma unroll
            for (int fr = 0; fr < 4; ++fr)
                #pragma unroll
                for (int fc = 0; fc < 4; ++fc)
                    acc[fr][fc] = MFMA16(a[fr], b[fc], acc[fr][fc], 0, 0, 0);
        }
        asm volatile("" ::: "memory");
        __builtin_amdgcn_s_barrier();
    }

    const int rB = row0 + wm * 64 + l4g * 4;
    const int cB = c0 + wn * 64 + l15;

    if (mode < 2) {
        ushort_t* O = (mode == 0) ? Q : Ko;
        const float2* Tm = Tab + (size_t)mode * (512 * 2048);
        #pragma unroll
        for (int fc = 0; fc < 4; ++fc) {
            const int col = cB + fc * 16;
            const float2* tp = Tm + ((size_t)(col >> 1) << 11);
            #pragma unroll
            for (int fr = 0; fr < 4; ++fr) {
                const int row = rB + fr * 16;
                const int l0 = row & 2047;
                float4 t01 = *(const float4*)(tp + l0);
                float4 t23 = *(const float4*)(tp + l0 + 2);
                float cs[8] = {t01.x, t01.y, t01.z, t01.w,
                               t23.x, t23.y, t23.z, t23.w};
                #pragma unroll
                for (int q = 0; q < 4; ++q) {
                    float v  = acc[fr][fc][q];
                    float pv = __shfl_xor(v, 1);
                    float cc = cs[2 * q], ss = cs[2 * q + 1];
                    float res = (lane & 1) ? fmaf(v, cc, pv * ss)
                                           : fmaf(v, cc, -pv * ss);
                    O[(size_t)(row + q) * DMODEL + col] = f2b(res);
                }
            }
        }
    } else {
        __syncthreads();
        #pragma unroll
        for (int fc = 0; fc < 4; ++fc)
            #pragma unroll
            for (int fr = 0; fr < 4; ++fr) {
                short4v pk;
                pk.x = (short)f2b(acc[fr][fc][0]);
                pk.y = (short)f2b(acc[fr][fc][1]);
                pk.z = (short)f2b(acc[fr][fc][2]);
                pk.w = (short)f2b(acc[fr][fc][3]);
                *(short4v*)(smem + (wn * 64 + fc * 16 + l15) * TPAD
                                 + wm * 64 + fr * 16 + l4g * 4) = pk;
            }
        __syncthreads();
        const int t = threadIdx.x;
        const int colV = c0 + (t >> 1);
        const int lhalf = (t & 1) * 64;
        const int b = row0 >> 11, lpos0 = (row0 & 2047) + lhalf;
        #pragma unroll
        for (int i = 0; i < 8; ++i) {
            short8 vv = *(const short8*)(smem + (t >> 1) * TPAD + lhalf + i * 8);
            *(short8*)(Vt + (size_t)b * (LSEQ * DMODEL)
                          + (size_t)colV * LSEQ + lpos0 + i * 8) = vv;
        }
    }
}

// ---------------------------------------------------------------------------
// Stage 1 (v10): 256x256 tile, 8-phase m201-template schedule.
// 512 threads = 8 waves (2M x 4N); per-wave output 128x64 (8x4 frags of
// 16x16); 16x16x32 MFMA, 16 per phase (one C-quadrant x K=64).
// LDS 128 KiB: A = buf*32768 + half*16384 (half=128 rows x 64 cols, linear
// 16B chunks, chunk XOR-swizzled by row&7 via pre-swizzled global source);
// B same at +65536. 1 half-tile (2 x gload_lds16) staged per phase.
// vmcnt(6) ONLY at phases 0 and 4 (2 loads x 3 half-tiles in flight).
// Stage stream for K-tile pair (2j+2 -> buf0, 2j+3 -> buf1):
//   ph2: b0.B0  ph3: b0.B1  ph4: b0.A0  ph5: b0.A1  ph6: b1.B0  ph7: b1.B1
//   ph0(next iter): b1.A0    ph1(next): b1.A1
// Legality: each region's last ds_read is >=1 phase (plus barrier) earlier.
// Ledger: prologue 6 half-tiles (12 loads: tile0 all, tile1 B). ph0 wait
// vmcnt(6) retires tile 2j's 8 loads; ph4 wait retires tile 2j+1's.
// Trailing iters stage OOB-into-workspace (never consumed; drained by the
// final vmcnt(0) before any LDS reuse).
// K-accumulation order per output element identical to qkv16 -> bitwise-
// identical Q/K/V.
// ---------------------------------------------------------------------------
__global__ __launch_bounds__(512) void qkv256_kernel(
    const ushort_t* __restrict__ Xb, const ushort_t* __restrict__ Wt,
    const float2* __restrict__ Tab,
    ushort_t* __restrict__ Q, ushort_t* __restrict__ Ko, ushort_t* __restrict__ Vt)
{
    extern __shared__ ushort_t smem[];   // 131072 B
    const int tid  = threadIdx.x;
    const int wave = tid >> 6, lane = tid & 63;
    const int wm = wave >> 2, wn = wave & 3;        // 2M x 4N
    const int l15 = lane & 15, l4g = lane >> 4, l7 = lane & 7;

    // XCD-bijective swizzle (grid % 8 == 0) + 4x4 supertile decode
    const int nwg = gridDim.x;
    const int orig = blockIdx.x;
    const int wg = (orig & 7) * (nwg >> 3) + (orig >> 3);
    const int sup = wg >> 4, inner = wg & 15;
    const int ct = (sup % 3) * 4 + (inner & 3);     // 0..11, mode = ct>>2
    const int rt = (sup / 3) * 4 + (inner >> 2);
    const int mode = ct >> 2;
    const int row0 = rt << 8;
    const int c0m  = (ct & 3) << 8;

    const char* gA = (const char*)Xb;
    const char* gB = (const char*)(Wt + (size_t)mode * (DMODEL * DMODEL));

    // per-thread staging source (pre-swizzled 16B chunk) for half h, load l:
    //   addr = o? + h*262144 + l*131072 + ktile*128   (bytes)
    const int t8 = tid >> 3;
    const int sw16 = ((tid & 7) ^ (t8 & 7)) << 4;
    const unsigned oA = (unsigned)((row0 + t8) * 2048) + sw16;
    const unsigned oB = (unsigned)((c0m + t8) * 2048) + sw16;
    char* ldsT = (char*)smem + tid * 16;

#define STG_A(d, h, kbyte) do {                                                  \
    GLOAD_LDS16(gA + oA + (h) * 262144u + (kbyte),                               \
                ldsT + (d) * 32768 + (h) * 16384);                               \
    GLOAD_LDS16(gA + oA + (h) * 262144u + 131072u + (kbyte),                     \
                ldsT + (d) * 32768 + (h) * 16384 + 8192);                        \
} while (0)
#define STG_B(d, h, kbyte) do {                                                  \
    GLOAD_LDS16(gB + oB + (h) * 262144u + (kbyte),                               \
                ldsT + 65536 + (d) * 32768 + (h) * 16384);                       \
    GLOAD_LDS16(gB + oB + (h) * 262144u + 131072u + (kbyte),                     \
                ldsT + 65536 + (d) * 32768 + (h) * 16384 + 8192);                \
} while (0)

    // ds_read base addresses (bytes); buf/frag selected via immediate offset
    int vaA[2], vaB[2];
    #pragma unroll
    for (int kh = 0; kh < 2; ++kh) {
        const int swz = (((kh * 4 + l4g) ^ l7) << 4);
        vaA[kh] = wm * 16384 + l15 * 128 + swz;
        vaB[kh] = 65536 + (wn >> 1) * 16384 + ((wn & 1) * 64 + l15) * 128 + swz;
    }

    float4v acc[8][4] = {};
    int4v af[4][2];      // current A quad (4 fr x 2 kh)
    int4v bf[4][2];      // all B frags (4 fc x 2 kh)

#define RD_AQ(D, Qm) do {                                                        \
    DSRN(af[0][0], vaA[0], (D) + (Qm) * 8192 + 0);                               \
    DSRN(af[0][1], vaA[1], (D) + (Qm) * 8192 + 0);                               \
    DSRN(af[1][0], vaA[0], (D) + (Qm) * 8192 + 2048);                            \
    DSRN(af[1][1], vaA[1], (D) + (Qm) * 8192 + 2048);                            \
    DSRN(af[2][0], vaA[0], (D) + (Qm) * 8192 + 4096);                            \
    DSRN(af[2][1], vaA[1], (D) + (Qm) * 8192 + 4096);                            \
    DSRN(af[3][0], vaA[0], (D) + (Qm) * 8192 + 6144);                            \
    DSRN(af[3][1], vaA[1], (D) + (Qm) * 8192 + 6144);                            \
} while (0)
#define RD_BP(D, Pn) do {                                                        \
    DSRN(bf[(Pn)*2+0][0], vaB[0], (D) + ((Pn)*2+0) * 2048);                      \
    DSRN(bf[(Pn)*2+0][1], vaB[1], (D) + ((Pn)*2+0) * 2048);                      \
    DSRN(bf[(Pn)*2+1][0], vaB[0], (D) + ((Pn)*2+1) * 2048);                      \
    DSRN(bf[(Pn)*2+1][1], vaB[1], (D) + ((Pn)*2+1) * 2048);                      \
} while (0)
#define LGKM0 do { asm volatile("s_waitcnt lgkmcnt(0)" ::: "memory");            \
                   __builtin_amdgcn_sched_barrier(0); } while (0)
#define MM_Q(Qm, Pn) do {                                                        \
    __builtin_amdgcn_s_setprio(1);                                               \
    _Pragma("unroll")                                                            \
    for (int fr = 0; fr < 4; ++fr)                                               \
        _Pragma("unroll")                                                        \
        for (int fc = 0; fc < 2; ++fc)                                           \
            _Pragma("unroll")                                                    \
            for (int kh = 0; kh < 2; ++kh)                                       \
                acc[(Qm)*4+fr][(Pn)*2+fc] =                                      \
                    MFMA16(as8(af[fr][kh]), as8(bf[(Pn)*2+fc][kh]),              \
                           acc[(Qm)*4+fr][(Pn)*2+fc], 0, 0, 0);                  \
    __builtin_amdgcn_s_setprio(0);                                               \
} while (0)
#define BAR __builtin_amdgcn_s_barrier()

    // prologue: tile0 (buf0 all 4 half-tiles) + tile1 (buf1 B halves)
    STG_B(0, 0, 0);   STG_B(0, 1, 0);
    STG_A(0, 0, 0);   STG_A(0, 1, 0);
    STG_B(1, 0, 128); STG_B(1, 1, 128);

    unsigned kb = 256;   // byte offset of K-tile 2j+2
    for (int j = 0; j < 8; ++j) {
        // ph0: stage b1.A0(2j+1); wait; reads buf0 A-quad0 + all-B-lo; q(0,0)
        STG_A(1, 0, kb - 128);
        asm volatile("s_waitcnt vmcnt(6)" ::: "memory");
        BAR;
        RD_AQ(0, 0); RD_BP(0, 0);
        LGKM0; MM_Q(0, 0); BAR;
        // ph1: reads B-hi; stage b1.A1(2j+1); q(0,1)
        RD_BP(0, 1);
        STG_A(1, 1, kb - 128);
        BAR; LGKM0; MM_Q(0, 1); BAR;
        // ph2: reads A-quad1; stage b0.B0(2j+2); q(1,0)
        RD_AQ(0, 1);
        STG_B(0, 0, kb);
        BAR; LGKM0; MM_Q(1, 0); BAR;
        // ph3: stage b0.B1(2j+2); q(1,1)
        STG_B(0, 1, kb);
        BAR; MM_Q(1, 1); BAR;
        // ph4: stage b0.A0(2j+2); wait; reads buf1; q(0,0)
        STG_A(0, 0, kb);
        asm volatile("s_waitcnt vmcnt(6)" ::: "memory");
        BAR;
        RD_AQ(32768, 0); RD_BP(32768, 0);
        LGKM0; MM_Q(0, 0); BAR;
        // ph5: reads B-hi; stage b0.A1(2j+2); q(0,1)
        RD_BP(32768, 1);
        STG_A(0, 1, kb);
        BAR; LGKM0; MM_Q(0, 1); BAR;
        // ph6: reads A-quad1; stage b1.B0(2j+3); q(1,0)
        RD_AQ(32768, 1);
        STG_B(1, 0, kb + 128);
        BAR; LGKM0; MM_Q(1, 0); BAR;
        // ph7: stage b1.B1(2j+3); q(1,1)
        STG_B(1, 1, kb + 128);
        BAR; MM_Q(1, 1); BAR;

        kb += 256;
    }
    // drain trailing (garbage) staging DMA before any LDS reuse / exit
    asm volatile("s_waitcnt vmcnt(0)" ::: "memory");
    BAR;

    // ------------------------- epilogue -------------------------
    // C/D: row = row0 + wm*128 + fr*16 + l4g*4 + q ; col = c0m + wn*64 +
    // fc*16 + l15   [m89 16x16 layout]
    const int rB = row0 + wm * 128 + l4g * 4;
    const int cB = c0m + wn * 64 + l15;

    if (mode < 2) {
        ushort_t* O = (mode == 0) ? Q : Ko;
        const float2* Tm = Tab + (size_t)mode * (512 * 2048);
        #pragma unroll
        for (int fc = 0; fc < 4; ++fc) {
            const int col = cB + fc * 16;
            const float2* tp = Tm + ((size_t)(col >> 1) << 11);
            #pragma unroll
            for (int fr = 0; fr < 8; ++fr) {
                const int row = rB + fr * 16;
                const int l0 = row & 2047;
                float4 t01 = *(const float4*)(tp + l0);
                float4 t23 = *(const float4*)(tp + l0 + 2);
                float cs[8] = {t01.x, t01.y, t01.z, t01.w,
                               t23.x, t23.y, t23.z, t23.w};
                #pragma unroll
                for (int q = 0; q < 4; ++q) {
                    float v  = acc[fr][fc][q];
                    float pv = __shfl_xor(v, 1);
                    float cc = cs[2 * q], ss = cs[2 * q + 1];
                    float res = (lane & 1) ? fmaf(v, cc, pv * ss)
                                           : fmaf(v, cc, -pv * ss);
                    O[(size_t)(row + q) * DMODEL + col] = f2b(res);
                }
            }
        }
    } else {
        // V: transpose 256x256 via LDS in two 128-col passes
        const int bidx = row0 >> 11, lpos0 = row0 & 2047;
        #pragma unroll
        for (int ph = 0; ph < 2; ++ph) {
            if ((wn >> 1) == ph) {
                const int colL = (wn & 1) * 64 + l15;   // + fc*16 -> 0..127
                const int rowL = wm * 128 + l4g * 4;    // + fr*16 -> 0..255
                #pragma unroll
                for (int fc = 0; fc < 4; ++fc)
                    #pragma unroll
                    for (int fr = 0; fr < 8; ++fr) {
                        short4v pk;
                        pk.x = (short)f2b(acc[fr][fc][0]);
                        pk.y = (short)f2b(acc[fr][fc][1]);
                        pk.z = (short)f2b(acc[fr][fc][2]);
                        pk.w = (short)f2b(acc[fr][fc][3]);
                        *(short4v*)(smem + (size_t)(colL + fc * 16) * 264
                                         + rowL + fr * 16) = pk;
                    }
            }
            __syncthreads();
            const int tc = tid >> 2, qtr = tid & 3;
            const int colV = c0m + ph * 128 + tc;
            #pragma unroll
            for (int i = 0; i < 8; ++i) {
                short8 vv = *(const short8*)(smem + (size_t)tc * 264
                                                  + qtr * 64 + i * 8);
                *(short8*)(Vt + (size_t)bidx * (LSEQ * DMODEL)
                              + (size_t)colV * LSEQ + lpos0 + qtr * 64 + i * 8) = vv;
            }
            __syncthreads();
        }
    }
#undef STG_A
#undef STG_B
#undef RD_AQ
#undef RD_BP
#undef LGKM0
#undef MM_Q
#undef BAR
}

// ---------------------------------------------------------------------------
// Stage 2 (R8-measured config): S = Q-hat . K-hat^T, banded, 128x128 tiles.
// ---------------------------------------------------------------------------
__global__ __launch_bounds__(256) void score_kernel(
    const ushort_t* __restrict__ Q, const ushort_t* __restrict__ Kc,
    ushort_t* __restrict__ S)
{
    const int t = blockIdx.x, z = blockIdx.z;
    int bi, bj;
    if (t < 3) { bi = (t > 0); bj = t - (t > 0); }
    else { int u = t - 3; bi = 2 + u / 3; bj = bi - 2 + u % 3; }

    __shared__ ushort_t As[2 * BM * BK], Bs[2 * BN * BK];
    float4v acc[4][4] = {};
    const size_t zoff = (size_t)z * (LSEQ * DMODEL);
    gemm16_core(Q + zoff, DMODEL, bi * BM, Kc + zoff, DMODEL, bj * BN,
                DMODEL, As, Bs, acc);

    const int wave = threadIdx.x >> 6, lane = threadIdx.x & 63;
    const int wm = wave >> 1, wn = wave & 1;
    const int l15 = lane & 15, l4g = lane >> 4;
    const int nB = bi * BM + wm * 64 + l4g * 4;
    const int mB = bj * BN + wn * 64 + l15;
    ushort_t* Sz = S + (size_t)z * LSEQ * LSEQ;
    #pragma unroll
    for (int fr = 0; fr < 4; ++fr)
        #pragma unroll
        for (int fc = 0; fc < 4; ++fc) {
            const int m = mB + fc * 16;
            #pragma unroll
            for (int q = 0; q < 4; ++q) {
                const int n = nB + fr * 16 + q;
                Sz[(size_t)n * LSEQ + m] =
                    (m <= n) ? f2b(acc[fr][fc][q]) : (ushort_t)0;
            }
        }
}

// ---------------------------------------------------------------------------
// Stage 3 (R8-measured config): O = S @ V, banded k-window.
// ---------------------------------------------------------------------------
__global__ __launch_bounds__(256) void av_kernel(
    const ushort_t* __restrict__ S, const ushort_t* __restrict__ Vt,
    float* __restrict__ Out)
{
    const int bx = blockIdx.x, bi = blockIdx.y, z = blockIdx.z;
    const int kLo = (bi >= 2) ? (bi - 2) * BM : 0;
    const int kW  = (bi + 1) * BM - kLo;
    __shared__ ushort_t As[2 * BM * BK], Bs[2 * BN * BK];
    float4v acc[4][4] = {};
    gemm16_core(S + (size_t)z * LSEQ * LSEQ + kLo, LSEQ, bi * BM,
                Vt + (size_t)z * ((size_t)LSEQ * DMODEL) + kLo, LSEQ, bx * BN,
                kW, As, Bs, acc);

    const int wave = threadIdx.x >> 6, lane = threadIdx.x & 63;
    const int wm = wave >> 1, wn = wave & 1;
    const int l15 = lane & 15, l4g = lane >> 4;
    const int rB = bi * BM + wm * 64 + l4g * 4;
    const int cB = bx * BN + wn * 64 + l15;
    float* Oz = Out + (size_t)z * ((size_t)LSEQ * DMODEL);
    #pragma unroll
    for (int fr = 0; fr < 4; ++fr)
        #pragma unroll
        for (int fc = 0; fc < 4; ++fc)
            #pragma unroll
            for (int q = 0; q < 4; ++q)
                Oz[(size_t)(rB + fr * 16 + q) * DMODEL + cB + fc * 16] =
                    acc[fr][fc][q];
}

// ---------------------------------------------------------------------------
extern "C" void kernel_launch(void* const* d_in, const int* in_sizes, int n_in,
                              void* d_out, int out_size, void* d_ws, size_t ws_size,
                              hipStream_t stream)
{
    const float* X  = (const float*)d_in[0];
    const float* Wq = (const float*)d_in[1];
    const float* Wk = (const float*)d_in[2];
    const float* Wv = (const float*)d_in[3];
    float* out = (float*)d_out;

    const size_t LH  = (size_t)LSEQ * DMODEL;
    const size_t WSZ = (size_t)DMODEL * DMODEL;
    const size_t SSZ = (size_t)LSEQ * LSEQ;
    const size_t TABN = (size_t)2 * 512 * 2048;

    size_t need4 = TABN * 8 + 2 * (3 * WSZ + 4 * (4 * LH + SSZ));
    const int bs = (ws_size >= need4) ? 4 : 1;

    float2* Tab = (float2*)d_ws;
    ushort_t* ws16 = (ushort_t*)(Tab + TABN);
    ushort_t* Wt = ws16;
    ushort_t* Xb = Wt + 3 * WSZ;
    ushort_t* Q  = Xb + (size_t)bs * LH;
    ushort_t* Kb = Q  + (size_t)bs * LH;
    ushort_t* Vt = Kb + (size_t)bs * LH;
    ushort_t* S  = Vt + (size_t)bs * LH;

    static int qkv256_ok = -1;
    if (qkv256_ok < 0) {
        hipError_t e = hipFuncSetAttribute(
            reinterpret_cast<const void*>(qkv256_kernel),
            hipFuncAttributeMaxDynamicSharedMemorySize, 131072);
        qkv256_ok = (e == hipSuccess) ? 1 : 0;
    }

    if (bs == 4) {
        prep_kernel<<<dim3(19456), 256, 0, stream>>>(
            Tab, Wq, Wk, Wv, Wt, (const float4*)X, (short4v*)Xb,
            (int)(4 * LH / 4));
        if (qkv256_ok)
            qkv256_kernel<<<dim3(384), 512, 131072, stream>>>(
                Xb, Wt, Tab, Q, Kb, Vt);
        else
            qkv16_kernel<<<dim3(24 * 4 * 16), 256, 0, stream>>>(
                Xb, Wt, Tab, Q, Kb, Vt);
        score_kernel<<<dim3(45, 1, 4), 256, 0, stream>>>(Q, Kb, S);
        av_kernel<<<dim3(8, 16, 4), 256, 0, stream>>>(S, Vt, out);
    } else {
        prep_kernel<<<dim3(11264), 256, 0, stream>>>(
            Tab, Wq, Wk, Wv, Wt, (const float4*)X, (short4v*)Xb, 0);
        for (int p = 0; p < 4; ++p) {
            const float* Xp = X + (size_t)p * LH;
            prep_kernel<<<dim3(2048), 256, 0, stream>>>(
                Tab, Wq, Wk, Wv, Wt,
                (const float4*)Xp, (short4v*)Xb, (int)(LH / 4));
            if (qkv256_ok)
                qkv256_kernel<<<dim3(96), 512, 131072, stream>>>(
                    Xb, Wt, Tab, Q, Kb, Vt);
            else
                qkv16_kernel<<<dim3(24 * 16), 256, 0, stream>>>(
                    Xb, Wt, Tab, Q, Kb, Vt);
            score_kernel<<<dim3(45, 1, 1), 256, 0, stream>>>(Q, Kb, S);
            av_kernel<<<dim3(8, 16, 1), 256, 0, stream>>>(S, Vt,
                out + (size_t)p * LH);
        }
    }
}